// Round 12
// baseline (211.866 us; speedup 1.0000x reference)
//
#include <hip/hip_runtime.h>
#include <cstdint>
#include <cstddef>

// Problem constants
#define NCB   8
#define KC    1024
#define SDIM  64
#define LDIM  512          // NCB*SDIM
#define BATCH 8192
#define INV_TAU (1.0f/0.07f)
#define K2E  20.60992915555662f   // log2(e)/TAU
#define STR8 272               // fp8 LDS row stride bytes (256 + 16 pad)
#define ASTR 68                // argmin LDS row stride in shorts (136 B)

typedef __bf16 bf16_t;
typedef bf16_t bf16x8 __attribute__((ext_vector_type(8)));
typedef float  floatx4 __attribute__((ext_vector_type(4)));
typedef int    intx8  __attribute__((ext_vector_type(8)));

__device__ __forceinline__ unsigned short f2bf(float f) {
    union { float f; unsigned int u; } c; c.f = f;
    unsigned int u = c.u;
    u += 0x7fffu + ((u >> 16) & 1u);   // round-to-nearest-even
    return (unsigned short)(u >> 16);
}
__device__ __forceinline__ float bf2f(unsigned short h) {
    union { unsigned int u; float f; } c; c.u = ((unsigned int)h) << 16;
    return c.f;
}
__device__ __forceinline__ float exp2_fast(float x) {
    float r; asm("v_exp_f32 %0, %1" : "=v"(r) : "v"(x)); return r;
}

// merge two sorted top-2 lists (m1<=m2, o1<=o2) -> top-2
__device__ __forceinline__ void merge2(float& m1, int& i1, float& m2, int& i2,
                                       float o1, int j1, float o2, int j2) {
    bool a = o1 < m1;
    float f1 = a ? o1 : m1; int g1 = a ? j1 : i1;
    float f2 = a ? m1 : o1; int g2 = a ? i1 : j1;
    bool b = o2 < m2;
    float f3 = b ? o2 : m2; int g3 = b ? j2 : i2;
    bool c = f3 < f2;
    m1 = f1; i1 = g1;
    m2 = c ? f3 : f2; i2 = c ? g3 : g2;
}

// ---------------------------------------------------------------------------
// K0 (merged prep): blocks 0..4095 split z into bf16 hi/lo; blocks 4096..4127
// compute e2 + split embeddings hi/lo + zero accumulators & finalize counter.
// (R10 lesson: single-pass bf16 argmin fails via exclusion-from-top-2; the
// hi/lo split is the verified precision floor — do not drop it again.)
// ---------------------------------------------------------------------------
__global__ __launch_bounds__(256) void
k_pre(const float* __restrict__ z, const float* __restrict__ emb,
      float* __restrict__ e2, unsigned short* __restrict__ eh,
      unsigned short* __restrict__ el, unsigned short* __restrict__ zh,
      unsigned short* __restrict__ zl, float* __restrict__ accs) {
    int bid = blockIdx.x;
    if (bid < 4096) {
        int id = bid * 256 + threadIdx.x;          // handles 4 floats of z
        float4 v = ((const float4*)z)[id];
        ushort4 h, l;
        h.x=f2bf(v.x); l.x=f2bf(v.x-bf2f(h.x));
        h.y=f2bf(v.y); l.y=f2bf(v.y-bf2f(h.y));
        h.z=f2bf(v.z); l.z=f2bf(v.z-bf2f(h.z));
        h.w=f2bf(v.w); l.w=f2bf(v.w-bf2f(h.w));
        ((ushort4*)zh)[id]=h; ((ushort4*)zl)[id]=l;
    } else {
        int id = (bid - 4096) * 256 + threadIdx.x; // 0..8191 = n*K+k
        const float4* e4 = (const float4*)(emb + (size_t)id * SDIM);
        ushort4* eh4 = (ushort4*)(eh + (size_t)id * SDIM);
        ushort4* el4 = (ushort4*)(el + (size_t)id * SDIM);
        float s0=0.f,s1=0.f,s2=0.f,s3=0.f;
#pragma unroll
        for (int i=0;i<16;i++){ float4 v=e4[i];
            s0=fmaf(v.x,v.x,s0); s1=fmaf(v.y,v.y,s1);
            s2=fmaf(v.z,v.z,s2); s3=fmaf(v.w,v.w,s3);
            ushort4 h, l;
            h.x=f2bf(v.x); l.x=f2bf(v.x-bf2f(h.x));
            h.y=f2bf(v.y); l.y=f2bf(v.y-bf2f(h.y));
            h.z=f2bf(v.z); l.z=f2bf(v.z-bf2f(h.z));
            h.w=f2bf(v.w); l.w=f2bf(v.w-bf2f(h.w));
            eh4[i]=h; el4[i]=l;
        }
        e2[id] = (s0+s1)+(s2+s3);
        if (id==0){ accs[0]=0.f; accs[1]=0.f; accs[2]=0.f; }
    }
}

// fp64 "relative distance" e2 - 2*z.e (z2 cancels in argmin ordering)
__device__ __forceinline__ double dist64d(const float* __restrict__ e,
                                          const float* __restrict__ zg) {
    double se=0.0, sz=0.0;
#pragma unroll 8
    for (int i=0;i<64;i++){ double ev=(double)e[i];
        se = fma(ev,ev,se); sz = fma(ev,(double)zg[i],sz); }
    return se - 2.0*sz;
}

// ---------------------------------------------------------------------------
// K2: MFMA argmin. R9-verified math (split-bf16 3-MFMA cross, per-lane top-2,
// butterfly + LDS merge, fp64 near-tie re-rank, gather+commit) with an LDS
// diet for occupancy: 64-code B tiles (16 jt), row stride 68 shorts (2-way
// bank aliasing = free), merge arrays aliased into the dead B region.
// 52.5 KB LDS -> 3 blocks/CU (12 waves) vs previous 78 KB/2 blocks.
// Grid dim3(64,8) natural mapping (load-bearing — R5 swizzle lesson).
// ---------------------------------------------------------------------------
__global__ __launch_bounds__(256,3) void
k_argmin(const unsigned short* __restrict__ zh, const unsigned short* __restrict__ zl,
         const unsigned short* __restrict__ eh, const unsigned short* __restrict__ el,
         const float* __restrict__ e2, const float* __restrict__ z,
         const float* __restrict__ emb, float* __restrict__ out_q,
         float* __restrict__ out_idx, float* __restrict__ accs) {
    __shared__ unsigned short Ah[128*ASTR], Al[128*ASTR];   // 34,816 B
    __shared__ unsigned short Bh[64*ASTR],  Bl[64*ASTR];    // 17,408 B
    __shared__ float e2s[64];                               //    256 B
    // merge scratch aliases Bh (4 KB needed, 8.7 KB available):
    float* mMf = (float*)Bh;           // [2][128][2] floats
    int*   mIf = ((int*)Bh) + 512;     // [2][128][2] ints

    const int tid = threadIdx.x;
    const int n   = blockIdx.y;
    const int i0  = blockIdx.x * 128;
    const int wid = tid >> 6, lane = tid & 63;
    const int wm = wid & 1, wn = wid >> 1;
    const int c  = lane & 15, qq = lane >> 4;

    // stage A (resident): 128 rows x 64 bf16, hi+lo
#pragma unroll
    for (int s=0;s<4;s++){
        int seg = tid + s*256; int r = seg>>3, sg = seg&7;
        size_t go = (size_t)(i0+r)*LDIM + n*SDIM + sg*8;
        *(uint4*)(&Ah[r*ASTR+sg*8]) = *(const uint4*)(zh + go);
        *(uint4*)(&Al[r*ASTR+sg*8]) = *(const uint4*)(zl + go);
    }

    float m1[16], m2[16]; int i1v[16], i2v[16];
#pragma unroll
    for (int j=0;j<16;j++){ m1[j]=3.4e38f; m2[j]=3.4e38f; i1v[j]=0; i2v[j]=0; }

    const unsigned short* ehn = eh + (size_t)n*KC*SDIM;
    const unsigned short* eln = el + (size_t)n*KC*SDIM;
    const float* e2n = e2 + n*KC;

    for (int jt=0; jt<16; jt++){
        const int j0 = jt*64;
        __syncthreads();
#pragma unroll
        for (int s=0;s<2;s++){        // stage B: 64 codes x 64 bf16, hi+lo
            int seg = tid + s*256; int r = seg>>3, sg = seg&7;
            size_t go = (size_t)(j0+r)*SDIM + sg*8;
            *(uint4*)(&Bh[r*ASTR+sg*8]) = *(const uint4*)(ehn + go);
            *(uint4*)(&Bl[r*ASTR+sg*8]) = *(const uint4*)(eln + go);
        }
        if (tid < 64) e2s[tid] = e2n[j0+tid];
        __syncthreads();

        floatx4 acc[4][2];
#pragma unroll
        for (int mt=0;mt<4;mt++)
#pragma unroll
            for (int nt=0;nt<2;nt++) acc[mt][nt] = (floatx4){0.f,0.f,0.f,0.f};

#pragma unroll
        for (int t=0;t<2;t++){
            bf16x8 ah[4], al[4], bh[2], bl[2];
#pragma unroll
            for (int mt=0;mt<4;mt++){
                ah[mt] = *(const bf16x8*)(&Ah[(wm*64+mt*16+c)*ASTR + t*32 + qq*8]);
                al[mt] = *(const bf16x8*)(&Al[(wm*64+mt*16+c)*ASTR + t*32 + qq*8]);
            }
#pragma unroll
            for (int nt=0;nt<2;nt++){
                bh[nt] = *(const bf16x8*)(&Bh[(wn*32+nt*16+c)*ASTR + t*32 + qq*8]);
                bl[nt] = *(const bf16x8*)(&Bl[(wn*32+nt*16+c)*ASTR + t*32 + qq*8]);
            }
#pragma unroll
            for (int mt=0;mt<4;mt++)
#pragma unroll
                for (int nt=0;nt<2;nt++){
                    acc[mt][nt] = __builtin_amdgcn_mfma_f32_16x16x32_bf16(ah[mt], bh[nt], acc[mt][nt], 0,0,0);
                    acc[mt][nt] = __builtin_amdgcn_mfma_f32_16x16x32_bf16(ah[mt], bl[nt], acc[mt][nt], 0,0,0);
                    acc[mt][nt] = __builtin_amdgcn_mfma_f32_16x16x32_bf16(al[mt], bh[nt], acc[mt][nt], 0,0,0);
                }
        }

        // dist = e2 - 2*cross ; per-lane running top-2 per row-slot
#pragma unroll
        for (int nt=0;nt<2;nt++){
            const int colb = wn*32 + nt*16 + c;
            float e2v = e2s[colb];
            int kidx = j0 + colb;
#pragma unroll
            for (int mt=0;mt<4;mt++)
#pragma unroll
                for (int reg=0;reg<4;reg++){
                    float d = fmaf(-2.0f, acc[mt][nt][reg], e2v);
                    int s = mt*4+reg;
                    float om1 = m1[s]; int oi1 = i1v[s];
                    bool lt1 = d < om1;
                    bool lt2 = d < m2[s];
                    m2[s]  = lt1 ? om1 : (lt2 ? d : m2[s]);
                    i2v[s] = lt1 ? oi1 : (lt2 ? kidx : i2v[s]);
                    m1[s]  = lt1 ? d : om1;
                    i1v[s] = lt1 ? kidx : oi1;
                }
        }
    }

    // butterfly top-2 merge across the 16 col-lanes
#pragma unroll
    for (int off=1; off<16; off<<=1){
#pragma unroll
        for (int s=0;s<16;s++){
            float o1 = __shfl_xor(m1[s], off);
            float o2 = __shfl_xor(m2[s], off);
            int   j1 = __shfl_xor(i1v[s], off);
            int   j2 = __shfl_xor(i2v[s], off);
            merge2(m1[s], i1v[s], m2[s], i2v[s], o1, j1, o2, j2);
        }
    }
    __syncthreads();   // all waves done reading B tiles before aliasing them
    if (c == 0){
#pragma unroll
        for (int s=0;s<16;s++){
            int row = wm*64 + (s>>2)*16 + qq*4 + (s&3);
            mMf[wn*256 + row*2 + 0] = m1[s]; mMf[wn*256 + row*2 + 1] = m2[s];
            mIf[wn*256 + row*2 + 0] = i1v[s]; mIf[wn*256 + row*2 + 1] = i2v[s];
        }
    }
    __syncthreads();

    if (tid < 128){
        int b = i0 + tid;
        float b1 = mMf[tid*2+0], b2v = mMf[tid*2+1];
        int  ii1 = mIf[tid*2+0], ii2 = mIf[tid*2+1];
        merge2(b1, ii1, b2v, ii2, mMf[256+tid*2+0], mIf[256+tid*2+0],
                                  mMf[256+tid*2+1], mIf[256+tid*2+1]);

        const float* eb = emb + (size_t)n*KC*SDIM;
        const float* zg = z + (size_t)b*LDIM + n*SDIM;
        if (b2v - b1 < 2e-2f) {
            double d1 = dist64d(eb + (size_t)ii1*SDIM, zg);
            double d2 = dist64d(eb + (size_t)ii2*SDIM, zg);
            if (d2 < d1 || (d2 == d1 && ii2 < ii1)) ii1 = ii2;
        }

        const float4* q4 = (const float4*)(eb + (size_t)ii1*SDIM);
        const float4* z4 = (const float4*)zg;
        float4* oq = (float4*)(out_q + (size_t)b*LDIM + n*SDIM);
        float cs = 0.f;
#pragma unroll
        for (int i=0;i<16;i++){
            float4 v = q4[i]; float4 zv = z4[i];
            oq[i] = v;
            float d0=v.x-zv.x, d1=v.y-zv.y, d2=v.z-zv.z, d3=v.w-zv.w;
            cs += d0*d0 + d1*d1 + d2*d2 + d3*d3;
        }
        out_idx[b*NCB + n] = (float)ii1;

        for (int off=32; off; off>>=1) cs += __shfl_down(cs, off);
        if ((tid & 63)==0) atomicAdd(&accs[0], cs);
    }
}

// ---------------------------------------------------------------------------
// K3: per-row L2 norms; write normalized FP8 (e4m3) copies + diag.
// ---------------------------------------------------------------------------
__global__ __launch_bounds__(256) void
k_norm(const float* __restrict__ z, const float* __restrict__ q,
       unsigned char* __restrict__ zn8, unsigned char* __restrict__ qn8,
       float* __restrict__ diag) {
    const int b = blockIdx.x, tid = threadIdx.x;
    const size_t base = (size_t)b*LDIM;
    float2 zv = ((const float2*)(z+base))[tid];
    float2 qv = ((const float2*)(q+base))[tid];
    float sz = zv.x*zv.x + zv.y*zv.y;
    float sq = qv.x*qv.x + qv.y*qv.y;
    float sqz= qv.x*zv.x + qv.y*zv.y;
    for (int off=32; off; off>>=1){
        sz+=__shfl_down(sz,off); sq+=__shfl_down(sq,off); sqz+=__shfl_down(sqz,off);
    }
    __shared__ float red[3][4];
    __shared__ float bc[2];
    int w = tid>>6;
    if ((tid&63)==0){ red[0][w]=sz; red[1][w]=sq; red[2][w]=sqz; }
    __syncthreads();
    if (tid==0){
        float tz = red[0][0]+red[0][1]+red[0][2]+red[0][3];
        float tq = red[1][0]+red[1][1]+red[1][2]+red[1][3];
        float tz_q = red[2][0]+red[2][1]+red[2][2]+red[2][3];
        float inz = 1.0f/fmaxf(sqrtf(tz), 1e-12f);
        float inq = 1.0f/fmaxf(sqrtf(tq), 1e-12f);
        bc[0]=inz; bc[1]=inq;
        diag[b] = tz_q*inz*inq*INV_TAU;
    }
    __syncthreads();
    float inz=bc[0], inq=bc[1];
    int pz = __builtin_amdgcn_cvt_pk_fp8_f32(zv.x*inz, zv.y*inz, 0, false);
    int pq = __builtin_amdgcn_cvt_pk_fp8_f32(qv.x*inq, qv.y*inq, 0, false);
    ((unsigned short*)(zn8+base))[tid] = (unsigned short)(pz & 0xffff);
    ((unsigned short*)(qn8+base))[tid] = (unsigned short)(pq & 0xffff);
}

// ---------------------------------------------------------------------------
// K4: logsumexp of logits = qn8 · zn8^T / TAU, fixed max M = 1/TAU, via
// MX-scaled fp8 MFMA 16x16x128 (scales = 1.0). R9-verified (~55 us).
// R6 geometry (dim3(64,8), 256 thr) — load-bearing, do not change.
// ---------------------------------------------------------------------------
__global__ __launch_bounds__(256,2) void
k_logits(const unsigned char* __restrict__ qn8, const unsigned char* __restrict__ zn8,
         float* __restrict__ Spart) {
    __shared__ unsigned char As[128*STR8];
    __shared__ unsigned char Bs[128*STR8];
    const int tid  = threadIdx.x;
    const int i0   = blockIdx.x * 128;
    const int chnk = blockIdx.y;           // 1024 cols each
    const int wid  = tid >> 6, lane = tid & 63;
    const int wm = wid & 1, wn = wid >> 1;
    const int c  = lane & 15, qq = lane >> 4;

    float S[16];
#pragma unroll
    for (int i=0;i<16;i++) S[i] = 0.f;

    for (int jt=0;jt<8;jt++){
        const int j0 = chnk*1024 + jt*128;
        floatx4 acc[4][4];
#pragma unroll
        for (int mt=0;mt<4;mt++)
#pragma unroll
            for (int nt=0;nt<4;nt++) acc[mt][nt] = (floatx4){0.f,0.f,0.f,0.f};

        for (int kk=0;kk<512;kk+=256){
            __syncthreads();
#pragma unroll
            for (int s=0;s<8;s++){
                int seg = tid + s*256;
                int r = seg >> 4, sg = seg & 15;
                *(uint4*)(&As[r*STR8 + sg*16]) =
                    *(const uint4*)(qn8 + (size_t)(i0+r)*LDIM + kk + sg*16);
            }
#pragma unroll
            for (int s=0;s<8;s++){
                int seg = tid + s*256;
                int r = seg >> 4, sg = seg & 15;
                *(uint4*)(&Bs[r*STR8 + sg*16]) =
                    *(const uint4*)(zn8 + (size_t)(j0+r)*LDIM + kk + sg*16);
            }
            __syncthreads();
#pragma unroll
            for (int t=0;t<2;t++){
                intx8 af[4], bfr[4];
#pragma unroll
                for (int mt=0;mt<4;mt++){
                    const unsigned char* p = &As[(wm*64+mt*16+c)*STR8 + t*128 + qq*32];
                    union { intx8 v; uint4 h[2]; } u;
                    u.h[0] = *(const uint4*)(p);
                    u.h[1] = *(const uint4*)(p+16);
                    af[mt] = u.v;
                }
#pragma unroll
                for (int nt=0;nt<4;nt++){
                    const unsigned char* p = &Bs[(wn*64+nt*16+c)*STR8 + t*128 + qq*32];
                    union { intx8 v; uint4 h[2]; } u;
                    u.h[0] = *(const uint4*)(p);
                    u.h[1] = *(const uint4*)(p+16);
                    bfr[nt] = u.v;
                }
#pragma unroll
                for (int mt=0;mt<4;mt++)
#pragma unroll
                    for (int nt=0;nt<4;nt++)
                        acc[mt][nt] = __builtin_amdgcn_mfma_scale_f32_16x16x128_f8f6f4(
                            af[mt], bfr[nt], acc[mt][nt],
                            0, 0,        // cbsz=FP8(e4m3), blgp=FP8(e4m3)
                            0, 127,      // scale_a opsel, scale_a (e8m0 1.0)
                            0, 127);     // scale_b opsel, scale_b
            }
        }

        // S[row-slot] += sum_nt 2^((dot-1)*K2E)
#pragma unroll
        for (int mt=0;mt<4;mt++)
#pragma unroll
            for (int reg=0;reg<4;reg++){
                float e0 = exp2_fast(fmaf(acc[mt][0][reg], K2E, -K2E));
                float e1 = exp2_fast(fmaf(acc[mt][1][reg], K2E, -K2E));
                float e2v= exp2_fast(fmaf(acc[mt][2][reg], K2E, -K2E));
                float e3 = exp2_fast(fmaf(acc[mt][3][reg], K2E, -K2E));
                S[mt*4+reg] += (e0+e1)+(e2v+e3);
            }
    }

    // reduce over the 16 col-lanes (disjoint cols, same rows)
#pragma unroll
    for (int off=1; off<16; off<<=1)
#pragma unroll
        for (int s=0;s<16;s++) S[s] += __shfl_xor(S[s], off);

    if (c == 0){
        const int p = chnk*2 + wn;             // 16 partial slots
#pragma unroll
        for (int mt=0;mt<4;mt++)
#pragma unroll
            for (int reg=0;reg<4;reg++){
                int row = i0 + wm*64 + mt*16 + qq*4 + reg;
                Spart[p*BATCH + row] = S[mt*4+reg];
            }
    }
}

// ---------------------------------------------------------------------------
// K5: combine 16 partials/row -> LSE - diag, reduce to accs[1]; the LAST
// block (device-scope counter accs[2]) also writes the two output scalars.
// ---------------------------------------------------------------------------
__global__ __launch_bounds__(256) void
k_finalize(const float* __restrict__ Spart, const float* __restrict__ diag,
           float* __restrict__ accs, float* __restrict__ out_s) {
    int r = blockIdx.x*256 + threadIdx.x;
    float Ssum = 0.f;
#pragma unroll
    for (int p=0;p<16;p++) Ssum += Spart[p*BATCH + r];
    float val = INV_TAU + logf(Ssum) - diag[r];
    for (int off=32; off; off>>=1) val += __shfl_down(val, off);
    if ((threadIdx.x & 63)==0) atomicAdd(&accs[1], val);
    __syncthreads();                       // drains this block's atomics
    if (threadIdx.x == 0){
        __threadfence();
        unsigned int old = __float_as_uint(atomicAdd(&accs[2], 1.0f));
        if (old == __float_as_uint(31.0f)) {   // 32nd (last) block
            __threadfence();
            float a0 = atomicAdd(&accs[0], 0.0f);
            float a1 = atomicAdd(&accs[1], 0.0f);
            out_s[0] = 2.0f*a0 / (float)((size_t)BATCH*LDIM);   // commit+embed
            out_s[1] = a1 / (float)BATCH;                       // contrastive
        }
    }
}

// ---------------------------------------------------------------------------
extern "C" void kernel_launch(void* const* d_in, const int* in_sizes, int n_in,
                              void* d_out, int out_size, void* d_ws, size_t ws_size,
                              hipStream_t stream) {
    const float* z   = (const float*)d_in[0];   // (B, L)
    const float* emb = (const float*)d_in[1];   // (NC, K, SD)
    float* out = (float*)d_out;
    float* out_q       = out;                   // B*L = 4194304
    float* out_scalars = out + 4194304;         // [commit, contrastive]
    float* out_idx     = out + 4194306;         // B*NC as float

    // ws layout (float offsets); ~19 MB total
    float* wsf   = (float*)d_ws;
    float* e2    = wsf;                         // 8192
    float* accs  = wsf + 8192;                  // [commit, contrastive, counter]
    float* diag  = wsf + 8704;                  // 8192
    float* Spart = wsf + 16896;                 // 16 slots used (32 reserved)
    unsigned short* zh = (unsigned short*)(Spart + 32*BATCH);  // B*L bf16 (8 MB)
    unsigned short* zl = zh + (size_t)BATCH*LDIM;              // B*L bf16 (8 MB)
    unsigned short* eh = zl + (size_t)BATCH*LDIM;              // NC*K*SD bf16
    unsigned short* el = eh + (size_t)NCB*KC*SDIM;             // NC*K*SD bf16
    // fp8 normalized copies alias zh's 8 MB (argmin reads zh before k_norm):
    unsigned char* qn8 = (unsigned char*)zh;                   // B*L fp8 (4 MB)
    unsigned char* zn8 = qn8 + (size_t)BATCH*LDIM;             // B*L fp8 (4 MB)

    k_pre    <<<4128,        256, 0, stream>>>(z, emb, e2, eh, el, zh, zl, accs);
    k_argmin <<<dim3(64,8),  256, 0, stream>>>(zh, zl, eh, el, e2, z, emb,
                                               out_q, out_idx, accs);
    k_norm   <<<BATCH,       256, 0, stream>>>(z, out_q, zn8, qn8, diag);
    k_logits <<<dim3(64,8),  256, 0, stream>>>(qn8, zn8, Spart);
    k_finalize<<<32,         256, 0, stream>>>(Spart, diag, accs, out_scalars);
}

// Round 13
// 188.707 us; speedup vs baseline: 1.1227x; 1.1227x over previous
//
#include <hip/hip_runtime.h>
#include <cstdint>
#include <cstddef>

// Problem constants
#define NCB   8
#define KC    1024
#define SDIM  64
#define LDIM  512          // NCB*SDIM
#define BATCH 8192
#define INV_TAU (1.0f/0.07f)
#define K2E  20.60992915555662f   // log2(e)/TAU
#define STR8 272               // fp8 LDS row stride bytes (256 + 16 pad)

typedef __bf16 bf16_t;
typedef bf16_t bf16x8 __attribute__((ext_vector_type(8)));
typedef float  floatx4 __attribute__((ext_vector_type(4)));
typedef int    intx8  __attribute__((ext_vector_type(8)));

__device__ __forceinline__ unsigned short f2bf(float f) {
    union { float f; unsigned int u; } c; c.f = f;
    unsigned int u = c.u;
    u += 0x7fffu + ((u >> 16) & 1u);   // round-to-nearest-even
    return (unsigned short)(u >> 16);
}
__device__ __forceinline__ float bf2f(unsigned short h) {
    union { unsigned int u; float f; } c; c.u = ((unsigned int)h) << 16;
    return c.f;
}
__device__ __forceinline__ float exp2_fast(float x) {
    float r; asm("v_exp_f32 %0, %1" : "=v"(r) : "v"(x)); return r;
}

// merge two sorted top-2 lists (m1<=m2, o1<=o2) -> top-2
__device__ __forceinline__ void merge2(float& m1, int& i1, float& m2, int& i2,
                                       float o1, int j1, float o2, int j2) {
    bool a = o1 < m1;
    float f1 = a ? o1 : m1; int g1 = a ? j1 : i1;
    float f2 = a ? m1 : o1; int g2 = a ? i1 : j1;
    bool b = o2 < m2;
    float f3 = b ? o2 : m2; int g3 = b ? j2 : i2;
    bool c = f3 < f2;
    m1 = f1; i1 = g1;
    m2 = c ? f3 : f2; i2 = c ? g3 : g2;
}

// ---------------------------------------------------------------------------
// K0 (merged prep): blocks 0..4095 split z into bf16 hi/lo; blocks 4096..4127
// compute e2 + split embeddings hi/lo + zero accumulators & finalize counter.
// (R10 lesson: single-pass bf16 argmin fails via exclusion-from-top-2; the
// hi/lo split is the verified precision floor — do not drop it again.)
// ---------------------------------------------------------------------------
__global__ __launch_bounds__(256) void
k_pre(const float* __restrict__ z, const float* __restrict__ emb,
      float* __restrict__ e2, unsigned short* __restrict__ eh,
      unsigned short* __restrict__ el, unsigned short* __restrict__ zh,
      unsigned short* __restrict__ zl, float* __restrict__ accs) {
    int bid = blockIdx.x;
    if (bid < 4096) {
        int id = bid * 256 + threadIdx.x;          // handles 4 floats of z
        float4 v = ((const float4*)z)[id];
        ushort4 h, l;
        h.x=f2bf(v.x); l.x=f2bf(v.x-bf2f(h.x));
        h.y=f2bf(v.y); l.y=f2bf(v.y-bf2f(h.y));
        h.z=f2bf(v.z); l.z=f2bf(v.z-bf2f(h.z));
        h.w=f2bf(v.w); l.w=f2bf(v.w-bf2f(h.w));
        ((ushort4*)zh)[id]=h; ((ushort4*)zl)[id]=l;
    } else {
        int id = (bid - 4096) * 256 + threadIdx.x; // 0..8191 = n*K+k
        const float4* e4 = (const float4*)(emb + (size_t)id * SDIM);
        ushort4* eh4 = (ushort4*)(eh + (size_t)id * SDIM);
        ushort4* el4 = (ushort4*)(el + (size_t)id * SDIM);
        float s0=0.f,s1=0.f,s2=0.f,s3=0.f;
#pragma unroll
        for (int i=0;i<16;i++){ float4 v=e4[i];
            s0=fmaf(v.x,v.x,s0); s1=fmaf(v.y,v.y,s1);
            s2=fmaf(v.z,v.z,s2); s3=fmaf(v.w,v.w,s3);
            ushort4 h, l;
            h.x=f2bf(v.x); l.x=f2bf(v.x-bf2f(h.x));
            h.y=f2bf(v.y); l.y=f2bf(v.y-bf2f(h.y));
            h.z=f2bf(v.z); l.z=f2bf(v.z-bf2f(h.z));
            h.w=f2bf(v.w); l.w=f2bf(v.w-bf2f(h.w));
            eh4[i]=h; el4[i]=l;
        }
        e2[id] = (s0+s1)+(s2+s3);
        if (id==0){ accs[0]=0.f; accs[1]=0.f; accs[2]=0.f; }
    }
}

// fp64 "relative distance" e2 - 2*z.e (z2 cancels in argmin ordering)
__device__ __forceinline__ double dist64d(const float* __restrict__ e,
                                          const float* __restrict__ zg) {
    double se=0.0, sz=0.0;
#pragma unroll 8
    for (int i=0;i<64;i++){ double ev=(double)e[i];
        se = fma(ev,ev,se); sz = fma(ev,(double)zg[i],sz); }
    return se - 2.0*sz;
}

// ---------------------------------------------------------------------------
// K2: MFMA argmin (R9/R11-verified local optimum: 128-code B tile, 8 jt,
// split-bf16 3-MFMA cross, 78 KB LDS, (256,2), VGPR 128 — 60.3 us).
// Defended from both directions: R8 barrier-halving +3 us, R12 LDS-diet
// (-38 us: spills + doubled barriers). Do not restructure without new evidence.
// Grid dim3(64,8) natural mapping (load-bearing — R5 swizzle lesson).
// ---------------------------------------------------------------------------
__global__ __launch_bounds__(256,2) void
k_argmin(const unsigned short* __restrict__ zh, const unsigned short* __restrict__ zl,
         const unsigned short* __restrict__ eh, const unsigned short* __restrict__ el,
         const float* __restrict__ e2, const float* __restrict__ z,
         const float* __restrict__ emb, float* __restrict__ out_q,
         float* __restrict__ out_idx, float* __restrict__ accs) {
    __shared__ unsigned short Ah[128*72], Al[128*72];
    __shared__ unsigned short Bh[128*72], Bl[128*72];
    __shared__ float e2s[128];
    __shared__ float mM[2][128][2];
    __shared__ int   mI[2][128][2];

    const int tid = threadIdx.x;
    const int n   = blockIdx.y;
    const int i0  = blockIdx.x * 128;
    const int wid = tid >> 6, lane = tid & 63;
    const int wm = wid & 1, wn = wid >> 1;
    const int c  = lane & 15, qq = lane >> 4;

#pragma unroll
    for (int s=0;s<4;s++){
        int seg = tid + s*256; int r = seg>>3, sg = seg&7;
        size_t go = (size_t)(i0+r)*LDIM + n*SDIM + sg*8;
        *(uint4*)(&Ah[r*72+sg*8]) = *(const uint4*)(zh + go);
        *(uint4*)(&Al[r*72+sg*8]) = *(const uint4*)(zl + go);
    }

    float m1[16], m2[16]; int i1v[16], i2v[16];
#pragma unroll
    for (int j=0;j<16;j++){ m1[j]=3.4e38f; m2[j]=3.4e38f; i1v[j]=0; i2v[j]=0; }

    const unsigned short* ehn = eh + (size_t)n*KC*SDIM;
    const unsigned short* eln = el + (size_t)n*KC*SDIM;
    const float* e2n = e2 + n*KC;

    for (int jt=0; jt<8; jt++){
        const int j0 = jt*128;
        __syncthreads();
#pragma unroll
        for (int s=0;s<4;s++){        // stage B: 128 codes x 64 bf16, hi+lo
            int seg = tid + s*256; int r = seg>>3, sg = seg&7;
            size_t go = (size_t)(j0+r)*SDIM + sg*8;
            *(uint4*)(&Bh[r*72+sg*8]) = *(const uint4*)(ehn + go);
            *(uint4*)(&Bl[r*72+sg*8]) = *(const uint4*)(eln + go);
        }
        if (tid < 128) e2s[tid] = e2n[j0+tid];
        __syncthreads();

        floatx4 acc[4][4];
#pragma unroll
        for (int mt=0;mt<4;mt++)
#pragma unroll
            for (int nt=0;nt<4;nt++) acc[mt][nt] = (floatx4){0.f,0.f,0.f,0.f};

#pragma unroll
        for (int t=0;t<2;t++){
            bf16x8 ah[4], al[4], bh[4], bl[4];
#pragma unroll
            for (int mt=0;mt<4;mt++){
                ah[mt] = *(const bf16x8*)(&Ah[(wm*64+mt*16+c)*72 + t*32 + qq*8]);
                al[mt] = *(const bf16x8*)(&Al[(wm*64+mt*16+c)*72 + t*32 + qq*8]);
            }
#pragma unroll
            for (int nt=0;nt<4;nt++){
                bh[nt] = *(const bf16x8*)(&Bh[(wn*64+nt*16+c)*72 + t*32 + qq*8]);
                bl[nt] = *(const bf16x8*)(&Bl[(wn*64+nt*16+c)*72 + t*32 + qq*8]);
            }
#pragma unroll
            for (int mt=0;mt<4;mt++)
#pragma unroll
                for (int nt=0;nt<4;nt++){
                    acc[mt][nt] = __builtin_amdgcn_mfma_f32_16x16x32_bf16(ah[mt], bh[nt], acc[mt][nt], 0,0,0);
                    acc[mt][nt] = __builtin_amdgcn_mfma_f32_16x16x32_bf16(ah[mt], bl[nt], acc[mt][nt], 0,0,0);
                    acc[mt][nt] = __builtin_amdgcn_mfma_f32_16x16x32_bf16(al[mt], bh[nt], acc[mt][nt], 0,0,0);
                }
        }

#pragma unroll
        for (int nt=0;nt<4;nt++){
            const int colb = wn*64 + nt*16 + c;
            float e2v = e2s[colb];
            int kidx = j0 + colb;
#pragma unroll
            for (int mt=0;mt<4;mt++)
#pragma unroll
                for (int reg=0;reg<4;reg++){
                    float d = fmaf(-2.0f, acc[mt][nt][reg], e2v);
                    int s = mt*4+reg;
                    float om1 = m1[s]; int oi1 = i1v[s];
                    bool lt1 = d < om1;
                    bool lt2 = d < m2[s];
                    m2[s]  = lt1 ? om1 : (lt2 ? d : m2[s]);
                    i2v[s] = lt1 ? oi1 : (lt2 ? kidx : i2v[s]);
                    m1[s]  = lt1 ? d : om1;
                    i1v[s] = lt1 ? kidx : oi1;
                }
        }
    }

#pragma unroll
    for (int off=1; off<16; off<<=1){
#pragma unroll
        for (int s=0;s<16;s++){
            float o1 = __shfl_xor(m1[s], off);
            float o2 = __shfl_xor(m2[s], off);
            int   j1 = __shfl_xor(i1v[s], off);
            int   j2 = __shfl_xor(i2v[s], off);
            merge2(m1[s], i1v[s], m2[s], i2v[s], o1, j1, o2, j2);
        }
    }
    if (c == 0){
#pragma unroll
        for (int s=0;s<16;s++){
            int row = wm*64 + (s>>2)*16 + qq*4 + (s&3);
            mM[wn][row][0] = m1[s]; mM[wn][row][1] = m2[s];
            mI[wn][row][0] = i1v[s]; mI[wn][row][1] = i2v[s];
        }
    }
    __syncthreads();

    if (tid < 128){
        int b = i0 + tid;
        float b1 = mM[0][tid][0], b2v = mM[0][tid][1];
        int  ii1 = mI[0][tid][0], ii2 = mI[0][tid][1];
        merge2(b1, ii1, b2v, ii2, mM[1][tid][0], mI[1][tid][0],
                                  mM[1][tid][1], mI[1][tid][1]);

        const float* eb = emb + (size_t)n*KC*SDIM;
        const float* zg = z + (size_t)b*LDIM + n*SDIM;
        if (b2v - b1 < 2e-2f) {
            double d1 = dist64d(eb + (size_t)ii1*SDIM, zg);
            double d2 = dist64d(eb + (size_t)ii2*SDIM, zg);
            if (d2 < d1 || (d2 == d1 && ii2 < ii1)) ii1 = ii2;
        }

        const float4* q4 = (const float4*)(eb + (size_t)ii1*SDIM);
        const float4* z4 = (const float4*)zg;
        float4* oq = (float4*)(out_q + (size_t)b*LDIM + n*SDIM);
        float cs = 0.f;
#pragma unroll
        for (int i=0;i<16;i++){
            float4 v = q4[i]; float4 zv = z4[i];
            oq[i] = v;
            float d0=v.x-zv.x, d1=v.y-zv.y, d2=v.z-zv.z, d3=v.w-zv.w;
            cs += d0*d0 + d1*d1 + d2*d2 + d3*d3;
        }
        out_idx[b*NCB + n] = (float)ii1;

        for (int off=32; off; off>>=1) cs += __shfl_down(cs, off);
        if ((tid & 63)==0) atomicAdd(&accs[0], cs);
    }
}

// ---------------------------------------------------------------------------
// K3: per-row L2 norms; write normalized FP8 (e4m3) copies + diag.
// ---------------------------------------------------------------------------
__global__ __launch_bounds__(256) void
k_norm(const float* __restrict__ z, const float* __restrict__ q,
       unsigned char* __restrict__ zn8, unsigned char* __restrict__ qn8,
       float* __restrict__ diag) {
    const int b = blockIdx.x, tid = threadIdx.x;
    const size_t base = (size_t)b*LDIM;
    float2 zv = ((const float2*)(z+base))[tid];
    float2 qv = ((const float2*)(q+base))[tid];
    float sz = zv.x*zv.x + zv.y*zv.y;
    float sq = qv.x*qv.x + qv.y*qv.y;
    float sqz= qv.x*zv.x + qv.y*zv.y;
    for (int off=32; off; off>>=1){
        sz+=__shfl_down(sz,off); sq+=__shfl_down(sq,off); sqz+=__shfl_down(sqz,off);
    }
    __shared__ float red[3][4];
    __shared__ float bc[2];
    int w = tid>>6;
    if ((tid&63)==0){ red[0][w]=sz; red[1][w]=sq; red[2][w]=sqz; }
    __syncthreads();
    if (tid==0){
        float tz = red[0][0]+red[0][1]+red[0][2]+red[0][3];
        float tq = red[1][0]+red[1][1]+red[1][2]+red[1][3];
        float tz_q = red[2][0]+red[2][1]+red[2][2]+red[2][3];
        float inz = 1.0f/fmaxf(sqrtf(tz), 1e-12f);
        float inq = 1.0f/fmaxf(sqrtf(tq), 1e-12f);
        bc[0]=inz; bc[1]=inq;
        diag[b] = tz_q*inz*inq*INV_TAU;
    }
    __syncthreads();
    float inz=bc[0], inq=bc[1];
    int pz = __builtin_amdgcn_cvt_pk_fp8_f32(zv.x*inz, zv.y*inz, 0, false);
    int pq = __builtin_amdgcn_cvt_pk_fp8_f32(qv.x*inq, qv.y*inq, 0, false);
    ((unsigned short*)(zn8+base))[tid] = (unsigned short)(pz & 0xffff);
    ((unsigned short*)(qn8+base))[tid] = (unsigned short)(pq & 0xffff);
}

// ---------------------------------------------------------------------------
// K4: logsumexp of logits = qn8 · zn8^T / TAU, fixed max M = 1/TAU, via
// MX-scaled fp8 MFMA 16x16x128 (scales = 1.0). R9/R11-verified (~55 us).
// R6 geometry (dim3(64,8), 256 thr) — load-bearing, do not change
// (R4/R5/R7 geometry variants all L2-thrashed: FETCH 266-344 MB).
// ---------------------------------------------------------------------------
__global__ __launch_bounds__(256,2) void
k_logits(const unsigned char* __restrict__ qn8, const unsigned char* __restrict__ zn8,
         float* __restrict__ Spart) {
    __shared__ unsigned char As[128*STR8];
    __shared__ unsigned char Bs[128*STR8];
    const int tid  = threadIdx.x;
    const int i0   = blockIdx.x * 128;
    const int chnk = blockIdx.y;           // 1024 cols each
    const int wid  = tid >> 6, lane = tid & 63;
    const int wm = wid & 1, wn = wid >> 1;
    const int c  = lane & 15, qq = lane >> 4;

    float S[16];
#pragma unroll
    for (int i=0;i<16;i++) S[i] = 0.f;

    for (int jt=0;jt<8;jt++){
        const int j0 = chnk*1024 + jt*128;
        floatx4 acc[4][4];
#pragma unroll
        for (int mt=0;mt<4;mt++)
#pragma unroll
            for (int nt=0;nt<4;nt++) acc[mt][nt] = (floatx4){0.f,0.f,0.f,0.f};

        for (int kk=0;kk<512;kk+=256){
            __syncthreads();
#pragma unroll
            for (int s=0;s<8;s++){
                int seg = tid + s*256;
                int r = seg >> 4, sg = seg & 15;
                *(uint4*)(&As[r*STR8 + sg*16]) =
                    *(const uint4*)(qn8 + (size_t)(i0+r)*LDIM + kk + sg*16);
            }
#pragma unroll
            for (int s=0;s<8;s++){
                int seg = tid + s*256;
                int r = seg >> 4, sg = seg & 15;
                *(uint4*)(&Bs[r*STR8 + sg*16]) =
                    *(const uint4*)(zn8 + (size_t)(j0+r)*LDIM + kk + sg*16);
            }
            __syncthreads();
#pragma unroll
            for (int t=0;t<2;t++){
                intx8 af[4], bfr[4];
#pragma unroll
                for (int mt=0;mt<4;mt++){
                    const unsigned char* p = &As[(wm*64+mt*16+c)*STR8 + t*128 + qq*32];
                    union { intx8 v; uint4 h[2]; } u;
                    u.h[0] = *(const uint4*)(p);
                    u.h[1] = *(const uint4*)(p+16);
                    af[mt] = u.v;
                }
#pragma unroll
                for (int nt=0;nt<4;nt++){
                    const unsigned char* p = &Bs[(wn*64+nt*16+c)*STR8 + t*128 + qq*32];
                    union { intx8 v; uint4 h[2]; } u;
                    u.h[0] = *(const uint4*)(p);
                    u.h[1] = *(const uint4*)(p+16);
                    bfr[nt] = u.v;
                }
#pragma unroll
                for (int mt=0;mt<4;mt++)
#pragma unroll
                    for (int nt=0;nt<4;nt++)
                        acc[mt][nt] = __builtin_amdgcn_mfma_scale_f32_16x16x128_f8f6f4(
                            af[mt], bfr[nt], acc[mt][nt],
                            0, 0,        // cbsz=FP8(e4m3), blgp=FP8(e4m3)
                            0, 127,      // scale_a opsel, scale_a (e8m0 1.0)
                            0, 127);     // scale_b opsel, scale_b
            }
        }

        // S[row-slot] += sum_nt 2^((dot-1)*K2E)
#pragma unroll
        for (int mt=0;mt<4;mt++)
#pragma unroll
            for (int reg=0;reg<4;reg++){
                float e0 = exp2_fast(fmaf(acc[mt][0][reg], K2E, -K2E));
                float e1 = exp2_fast(fmaf(acc[mt][1][reg], K2E, -K2E));
                float e2v= exp2_fast(fmaf(acc[mt][2][reg], K2E, -K2E));
                float e3 = exp2_fast(fmaf(acc[mt][3][reg], K2E, -K2E));
                S[mt*4+reg] += (e0+e1)+(e2v+e3);
            }
    }

    // reduce over the 16 col-lanes (disjoint cols, same rows)
#pragma unroll
    for (int off=1; off<16; off<<=1)
#pragma unroll
        for (int s=0;s<16;s++) S[s] += __shfl_xor(S[s], off);

    if (c == 0){
        const int p = chnk*2 + wn;             // 16 partial slots
#pragma unroll
        for (int mt=0;mt<4;mt++)
#pragma unroll
            for (int reg=0;reg<4;reg++){
                int row = i0 + wm*64 + mt*16 + qq*4 + reg;
                Spart[p*BATCH + row] = S[mt*4+reg];
            }
    }
}

// ---------------------------------------------------------------------------
// K5: combine 16 partials/row -> LSE - diag, reduce to accs[1]; the LAST
// block (device-scope counter accs[2]) also writes the two output scalars.
// ---------------------------------------------------------------------------
__global__ __launch_bounds__(256) void
k_finalize(const float* __restrict__ Spart, const float* __restrict__ diag,
           float* __restrict__ accs, float* __restrict__ out_s) {
    int r = blockIdx.x*256 + threadIdx.x;
    float Ssum = 0.f;
#pragma unroll
    for (int p=0;p<16;p++) Ssum += Spart[p*BATCH + r];
    float val = INV_TAU + logf(Ssum) - diag[r];
    for (int off=32; off; off>>=1) val += __shfl_down(val, off);
    if ((threadIdx.x & 63)==0) atomicAdd(&accs[1], val);
    __syncthreads();                       // drains this block's atomics
    if (threadIdx.x == 0){
        __threadfence();
        unsigned int old = __float_as_uint(atomicAdd(&accs[2], 1.0f));
        if (old == __float_as_uint(31.0f)) {   // 32nd (last) block
            __threadfence();
            float a0 = atomicAdd(&accs[0], 0.0f);
            float a1 = atomicAdd(&accs[1], 0.0f);
            out_s[0] = 2.0f*a0 / (float)((size_t)BATCH*LDIM);   // commit+embed
            out_s[1] = a1 / (float)BATCH;                       // contrastive
        }
    }
}

// ---------------------------------------------------------------------------
extern "C" void kernel_launch(void* const* d_in, const int* in_sizes, int n_in,
                              void* d_out, int out_size, void* d_ws, size_t ws_size,
                              hipStream_t stream) {
    const float* z   = (const float*)d_in[0];   // (B, L)
    const float* emb = (const float*)d_in[1];   // (NC, K, SD)
    float* out = (float*)d_out;
    float* out_q       = out;                   // B*L = 4194304
    float* out_scalars = out + 4194304;         // [commit, contrastive]
    float* out_idx     = out + 4194306;         // B*NC as float

    // ws layout (float offsets); ~19 MB total
    float* wsf   = (float*)d_ws;
    float* e2    = wsf;                         // 8192
    float* accs  = wsf + 8192;                  // [commit, contrastive, counter]
    float* diag  = wsf + 8704;                  // 8192
    float* Spart = wsf + 16896;                 // 16 slots used (32 reserved)
    unsigned short* zh = (unsigned short*)(Spart + 32*BATCH);  // B*L bf16 (8 MB)
    unsigned short* zl = zh + (size_t)BATCH*LDIM;              // B*L bf16 (8 MB)
    unsigned short* eh = zl + (size_t)BATCH*LDIM;              // NC*K*SD bf16
    unsigned short* el = eh + (size_t)NCB*KC*SDIM;             // NC*K*SD bf16
    // fp8 normalized copies alias zh's 8 MB (argmin reads zh before k_norm):
    unsigned char* qn8 = (unsigned char*)zh;                   // B*L fp8 (4 MB)
    unsigned char* zn8 = qn8 + (size_t)BATCH*LDIM;             // B*L fp8 (4 MB)

    k_pre    <<<4128,        256, 0, stream>>>(z, emb, e2, eh, el, zh, zl, accs);
    k_argmin <<<dim3(64,8),  256, 0, stream>>>(zh, zl, eh, el, e2, z, emb,
                                               out_q, out_idx, accs);
    k_norm   <<<BATCH,       256, 0, stream>>>(z, out_q, zn8, qn8, diag);
    k_logits <<<dim3(64,8),  256, 0, stream>>>(qn8, zn8, Spart);
    k_finalize<<<32,         256, 0, stream>>>(Spart, diag, accs, out_scalars);
}

// Round 14
// 173.339 us; speedup vs baseline: 1.2223x; 1.0887x over previous
//
#include <hip/hip_runtime.h>
#include <cstdint>
#include <cstddef>

// Problem constants
#define NCB   8
#define KC    1024
#define SDIM  64
#define LDIM  512          // NCB*SDIM
#define BATCH 8192
#define INV_TAU (1.0f/0.07f)
#define K2E  20.60992915555662f   // log2(e)/TAU
#define STR8 272               // fp8 LDS row stride bytes (256 + 16 pad)
#define DBIAS 256.0f           // dist bias: dist+256 in [174,466) -> positive, 2 binades

typedef __bf16 bf16_t;
typedef bf16_t bf16x8 __attribute__((ext_vector_type(8)));
typedef float  floatx4 __attribute__((ext_vector_type(4)));
typedef int    intx8  __attribute__((ext_vector_type(8)));

__device__ __forceinline__ unsigned short f2bf(float f) {
    union { float f; unsigned int u; } c; c.f = f;
    unsigned int u = c.u;
    u += 0x7fffu + ((u >> 16) & 1u);   // round-to-nearest-even
    return (unsigned short)(u >> 16);
}
__device__ __forceinline__ float bf2f(unsigned short h) {
    union { unsigned int u; float f; } c; c.u = ((unsigned int)h) << 16;
    return c.f;
}
__device__ __forceinline__ float exp2_fast(float x) {
    float r; asm("v_exp_f32 %0, %1" : "=v"(r) : "v"(x)); return r;
}

// ---------------------------------------------------------------------------
// K0: embeddings only (32 blocks): e2 + bf16 hi/lo split + zero accs.
// (z hi/lo split folded into k_argmin's A-staging — saves 32 MB of HBM.)
// ---------------------------------------------------------------------------
__global__ __launch_bounds__(256) void
k_pre(const float* __restrict__ emb, float* __restrict__ e2,
      unsigned short* __restrict__ eh, unsigned short* __restrict__ el,
      float* __restrict__ accs) {
    int id = blockIdx.x * 256 + threadIdx.x;   // 0..8191 = n*K+k
    const float4* e4 = (const float4*)(emb + (size_t)id * SDIM);
    ushort4* eh4 = (ushort4*)(eh + (size_t)id * SDIM);
    ushort4* el4 = (ushort4*)(el + (size_t)id * SDIM);
    float s0=0.f,s1=0.f,s2=0.f,s3=0.f;
#pragma unroll
    for (int i=0;i<16;i++){ float4 v=e4[i];
        s0=fmaf(v.x,v.x,s0); s1=fmaf(v.y,v.y,s1);
        s2=fmaf(v.z,v.z,s2); s3=fmaf(v.w,v.w,s3);
        ushort4 h, l;
        h.x=f2bf(v.x); l.x=f2bf(v.x-bf2f(h.x));
        h.y=f2bf(v.y); l.y=f2bf(v.y-bf2f(h.y));
        h.z=f2bf(v.z); l.z=f2bf(v.z-bf2f(h.z));
        h.w=f2bf(v.w); l.w=f2bf(v.w-bf2f(h.w));
        eh4[i]=h; el4[i]=l;
    }
    e2[id] = (s0+s1)+(s2+s3);
    if (id==0){ accs[0]=0.f; accs[1]=0.f; accs[2]=0.f; }
}

// fp64 "relative distance" e2 - 2*z.e (z2 cancels in argmin ordering)
__device__ __forceinline__ double dist64d(const float* __restrict__ e,
                                          const float* __restrict__ zg) {
    double se=0.0, sz=0.0;
#pragma unroll 8
    for (int i=0;i<64;i++){ double ev=(double)e[i];
        se = fma(ev,ev,se); sz = fma(ev,(double)zg[i],sz); }
    return se - 2.0*sz;
}

// ---------------------------------------------------------------------------
// K2: MFMA argmin (R9/R11 structure: 128-code B tile, 8 jt, split-bf16
// 3-MFMA cross — verified local optimum). Two R14 deltas:
//  (a) A-staging reads z fp32 and does the hi/lo split in-kernel (bit-
//      identical to the old k_pre conversion; same 32 KB/block traffic).
//  (b) packed-key top-2: key = (bits(dist+256) & ~0x3FF) | kidx.
//      dist+256 in [174,466) -> positive, monotone; <=0.031 quantization
//      absorbed by the widened 0.08 fp64 re-rank window. Per-dist 9->5 ops,
//      state regs 64->32, butterfly shuffles halved.
// Grid dim3(64,8) natural mapping (load-bearing — R5 swizzle lesson).
// ---------------------------------------------------------------------------
__global__ __launch_bounds__(256,2) void
k_argmin(const unsigned short* __restrict__ eh, const unsigned short* __restrict__ el,
         const float* __restrict__ e2, const float* __restrict__ z,
         const float* __restrict__ emb, float* __restrict__ out_q,
         float* __restrict__ out_idx, float* __restrict__ accs) {
    __shared__ unsigned short Ah[128*72], Al[128*72];
    __shared__ unsigned short Bh[128*72], Bl[128*72];
    __shared__ float e2s[128];
    __shared__ unsigned int mK[2][128][2];

    const int tid = threadIdx.x;
    const int n   = blockIdx.y;
    const int i0  = blockIdx.x * 128;
    const int wid = tid >> 6, lane = tid & 63;
    const int wm = wid & 1, wn = wid >> 1;
    const int c  = lane & 15, qq = lane >> 4;

    // stage A (resident): read z fp32, split hi/lo in-kernel (once per block)
#pragma unroll
    for (int s=0;s<8;s++){
        int seg = tid + s*256;           // 2048 segs; 16 float4-segs per row
        int r = seg >> 4, sg = seg & 15;
        float4 v = *(const float4*)(z + (size_t)(i0+r)*LDIM + n*SDIM + sg*4);
        ushort4 h, l;
        h.x=f2bf(v.x); l.x=f2bf(v.x-bf2f(h.x));
        h.y=f2bf(v.y); l.y=f2bf(v.y-bf2f(h.y));
        h.z=f2bf(v.z); l.z=f2bf(v.z-bf2f(h.z));
        h.w=f2bf(v.w); l.w=f2bf(v.w-bf2f(h.w));
        *(ushort4*)(&Ah[r*72+sg*4]) = h;
        *(ushort4*)(&Al[r*72+sg*4]) = l;
    }

    unsigned int k1[16], k2[16];
#pragma unroll
    for (int j=0;j<16;j++){ k1[j]=0xFFFFFFFFu; k2[j]=0xFFFFFFFFu; }

    const unsigned short* ehn = eh + (size_t)n*KC*SDIM;
    const unsigned short* eln = el + (size_t)n*KC*SDIM;
    const float* e2n = e2 + n*KC;

    for (int jt=0; jt<8; jt++){
        const int j0 = jt*128;
        __syncthreads();
#pragma unroll
        for (int s=0;s<4;s++){        // stage B: 128 codes x 64 bf16, hi+lo
            int seg = tid + s*256; int r = seg>>3, sg = seg&7;
            size_t go = (size_t)(j0+r)*SDIM + sg*8;
            *(uint4*)(&Bh[r*72+sg*8]) = *(const uint4*)(ehn + go);
            *(uint4*)(&Bl[r*72+sg*8]) = *(const uint4*)(eln + go);
        }
        if (tid < 128) e2s[tid] = e2n[j0+tid] + DBIAS;
        __syncthreads();

        floatx4 acc[4][4];
#pragma unroll
        for (int mt=0;mt<4;mt++)
#pragma unroll
            for (int nt=0;nt<4;nt++) acc[mt][nt] = (floatx4){0.f,0.f,0.f,0.f};

#pragma unroll
        for (int t=0;t<2;t++){
            bf16x8 ah[4], al[4], bh[4], bl[4];
#pragma unroll
            for (int mt=0;mt<4;mt++){
                ah[mt] = *(const bf16x8*)(&Ah[(wm*64+mt*16+c)*72 + t*32 + qq*8]);
                al[mt] = *(const bf16x8*)(&Al[(wm*64+mt*16+c)*72 + t*32 + qq*8]);
            }
#pragma unroll
            for (int nt=0;nt<4;nt++){
                bh[nt] = *(const bf16x8*)(&Bh[(wn*64+nt*16+c)*72 + t*32 + qq*8]);
                bl[nt] = *(const bf16x8*)(&Bl[(wn*64+nt*16+c)*72 + t*32 + qq*8]);
            }
#pragma unroll
            for (int mt=0;mt<4;mt++)
#pragma unroll
                for (int nt=0;nt<4;nt++){
                    acc[mt][nt] = __builtin_amdgcn_mfma_f32_16x16x32_bf16(ah[mt], bh[nt], acc[mt][nt], 0,0,0);
                    acc[mt][nt] = __builtin_amdgcn_mfma_f32_16x16x32_bf16(ah[mt], bl[nt], acc[mt][nt], 0,0,0);
                    acc[mt][nt] = __builtin_amdgcn_mfma_f32_16x16x32_bf16(al[mt], bh[nt], acc[mt][nt], 0,0,0);
                }
        }

        // biased dist -> packed key -> branchless top-2 (min/max chains)
#pragma unroll
        for (int nt=0;nt<4;nt++){
            const int colb = wn*64 + nt*16 + c;
            float e2v = e2s[colb];
            unsigned int kidx = (unsigned int)(j0 + colb);
#pragma unroll
            for (int mt=0;mt<4;mt++)
#pragma unroll
                for (int reg=0;reg<4;reg++){
                    float d = fmaf(-2.0f, acc[mt][nt][reg], e2v);
                    unsigned int key = (__float_as_uint(d) & 0xFFFFFC00u) | kidx;
                    int s = mt*4+reg;
                    unsigned int o1 = k1[s];
                    k2[s] = min(k2[s], max(key, o1));
                    k1[s] = min(o1, key);
                }
        }
    }

    // butterfly top-2 merge across the 16 col-lanes
#pragma unroll
    for (int off=1; off<16; off<<=1){
#pragma unroll
        for (int s=0;s<16;s++){
            unsigned int o1 = __shfl_xor(k1[s], off);
            unsigned int o2 = __shfl_xor(k2[s], off);
            unsigned int n1 = min(k1[s], o1);
            k2[s] = min( max(k1[s], o1), min(k2[s], o2) );
            k1[s] = n1;
        }
    }
    if (c == 0){
#pragma unroll
        for (int s=0;s<16;s++){
            int row = wm*64 + (s>>2)*16 + qq*4 + (s&3);
            mK[wn][row][0] = k1[s]; mK[wn][row][1] = k2[s];
        }
    }
    __syncthreads();

    if (tid < 128){
        int b = i0 + tid;
        unsigned int a1 = mK[0][tid][0], a2 = mK[0][tid][1];
        unsigned int c1 = mK[1][tid][0], c2 = mK[1][tid][1];
        unsigned int f1 = min(a1, c1);
        unsigned int f2 = min( max(a1, c1), min(a2, c2) );
        int ii1 = (int)(f1 & 0x3FFu);
        int ii2 = (int)(f2 & 0x3FFu);
        float d1q = __uint_as_float(f1 & 0xFFFFFC00u);
        float d2q = __uint_as_float(f2 & 0xFFFFFC00u);

        const float* eb = emb + (size_t)n*KC*SDIM;
        const float* zg = z + (size_t)b*LDIM + n*SDIM;
        if (d2q - d1q < 0.08f) {   // window covers quantization (0.031) + bf16 err
            double d1 = dist64d(eb + (size_t)ii1*SDIM, zg);
            double d2 = dist64d(eb + (size_t)ii2*SDIM, zg);
            if (d2 < d1 || (d2 == d1 && ii2 < ii1)) ii1 = ii2;
        }

        const float4* q4 = (const float4*)(eb + (size_t)ii1*SDIM);
        const float4* z4 = (const float4*)zg;
        float4* oq = (float4*)(out_q + (size_t)b*LDIM + n*SDIM);
        float cs = 0.f;
#pragma unroll
        for (int i=0;i<16;i++){
            float4 v = q4[i]; float4 zv = z4[i];
            oq[i] = v;
            float d0=v.x-zv.x, d1=v.y-zv.y, d2=v.z-zv.z, d3=v.w-zv.w;
            cs += d0*d0 + d1*d1 + d2*d2 + d3*d3;
        }
        out_idx[b*NCB + n] = (float)ii1;

        for (int off=32; off; off>>=1) cs += __shfl_down(cs, off);
        if ((tid & 63)==0) atomicAdd(&accs[0], cs);
    }
}

// ---------------------------------------------------------------------------
// K3: per-row L2 norms; write normalized FP8 (e4m3) copies + diag.
// ---------------------------------------------------------------------------
__global__ __launch_bounds__(256) void
k_norm(const float* __restrict__ z, const float* __restrict__ q,
       unsigned char* __restrict__ zn8, unsigned char* __restrict__ qn8,
       float* __restrict__ diag) {
    const int b = blockIdx.x, tid = threadIdx.x;
    const size_t base = (size_t)b*LDIM;
    float2 zv = ((const float2*)(z+base))[tid];
    float2 qv = ((const float2*)(q+base))[tid];
    float sz = zv.x*zv.x + zv.y*zv.y;
    float sq = qv.x*qv.x + qv.y*qv.y;
    float sqz= qv.x*zv.x + qv.y*zv.y;
    for (int off=32; off; off>>=1){
        sz+=__shfl_down(sz,off); sq+=__shfl_down(sq,off); sqz+=__shfl_down(sqz,off);
    }
    __shared__ float red[3][4];
    __shared__ float bc[2];
    int w = tid>>6;
    if ((tid&63)==0){ red[0][w]=sz; red[1][w]=sq; red[2][w]=sqz; }
    __syncthreads();
    if (tid==0){
        float tz = red[0][0]+red[0][1]+red[0][2]+red[0][3];
        float tq = red[1][0]+red[1][1]+red[1][2]+red[1][3];
        float tz_q = red[2][0]+red[2][1]+red[2][2]+red[2][3];
        float inz = 1.0f/fmaxf(sqrtf(tz), 1e-12f);
        float inq = 1.0f/fmaxf(sqrtf(tq), 1e-12f);
        bc[0]=inz; bc[1]=inq;
        diag[b] = tz_q*inz*inq*INV_TAU;
    }
    __syncthreads();
    float inz=bc[0], inq=bc[1];
    int pz = __builtin_amdgcn_cvt_pk_fp8_f32(zv.x*inz, zv.y*inz, 0, false);
    int pq = __builtin_amdgcn_cvt_pk_fp8_f32(qv.x*inq, qv.y*inq, 0, false);
    ((unsigned short*)(zn8+base))[tid] = (unsigned short)(pz & 0xffff);
    ((unsigned short*)(qn8+base))[tid] = (unsigned short)(pq & 0xffff);
}

// ---------------------------------------------------------------------------
// K4: logsumexp of logits = qn8 · zn8^T / TAU, fixed max M = 1/TAU, via
// MX-scaled fp8 MFMA 16x16x128 (scales = 1.0). R9/R11/R13-verified (~55 us).
// R6 geometry (dim3(64,8), 256 thr) — load-bearing, do not change
// (R4/R5/R7 geometry variants all L2-thrashed: FETCH 266-344 MB).
// ---------------------------------------------------------------------------
__global__ __launch_bounds__(256,2) void
k_logits(const unsigned char* __restrict__ qn8, const unsigned char* __restrict__ zn8,
         float* __restrict__ Spart) {
    __shared__ unsigned char As[128*STR8];
    __shared__ unsigned char Bs[128*STR8];
    const int tid  = threadIdx.x;
    const int i0   = blockIdx.x * 128;
    const int chnk = blockIdx.y;           // 1024 cols each
    const int wid  = tid >> 6, lane = tid & 63;
    const int wm = wid & 1, wn = wid >> 1;
    const int c  = lane & 15, qq = lane >> 4;

    float S[16];
#pragma unroll
    for (int i=0;i<16;i++) S[i] = 0.f;

    for (int jt=0;jt<8;jt++){
        const int j0 = chnk*1024 + jt*128;
        floatx4 acc[4][4];
#pragma unroll
        for (int mt=0;mt<4;mt++)
#pragma unroll
            for (int nt=0;nt<4;nt++) acc[mt][nt] = (floatx4){0.f,0.f,0.f,0.f};

        for (int kk=0;kk<512;kk+=256){
            __syncthreads();
#pragma unroll
            for (int s=0;s<8;s++){
                int seg = tid + s*256;
                int r = seg >> 4, sg = seg & 15;
                *(uint4*)(&As[r*STR8 + sg*16]) =
                    *(const uint4*)(qn8 + (size_t)(i0+r)*LDIM + kk + sg*16);
            }
#pragma unroll
            for (int s=0;s<8;s++){
                int seg = tid + s*256;
                int r = seg >> 4, sg = seg & 15;
                *(uint4*)(&Bs[r*STR8 + sg*16]) =
                    *(const uint4*)(zn8 + (size_t)(j0+r)*LDIM + kk + sg*16);
            }
            __syncthreads();
#pragma unroll
            for (int t=0;t<2;t++){
                intx8 af[4], bfr[4];
#pragma unroll
                for (int mt=0;mt<4;mt++){
                    const unsigned char* p = &As[(wm*64+mt*16+c)*STR8 + t*128 + qq*32];
                    union { intx8 v; uint4 h[2]; } u;
                    u.h[0] = *(const uint4*)(p);
                    u.h[1] = *(const uint4*)(p+16);
                    af[mt] = u.v;
                }
#pragma unroll
                for (int nt=0;nt<4;nt++){
                    const unsigned char* p = &Bs[(wn*64+nt*16+c)*STR8 + t*128 + qq*32];
                    union { intx8 v; uint4 h[2]; } u;
                    u.h[0] = *(const uint4*)(p);
                    u.h[1] = *(const uint4*)(p+16);
                    bfr[nt] = u.v;
                }
#pragma unroll
                for (int mt=0;mt<4;mt++)
#pragma unroll
                    for (int nt=0;nt<4;nt++)
                        acc[mt][nt] = __builtin_amdgcn_mfma_scale_f32_16x16x128_f8f6f4(
                            af[mt], bfr[nt], acc[mt][nt],
                            0, 0,        // cbsz=FP8(e4m3), blgp=FP8(e4m3)
                            0, 127,      // scale_a opsel, scale_a (e8m0 1.0)
                            0, 127);     // scale_b opsel, scale_b
            }
        }

        // S[row-slot] += sum_nt 2^((dot-1)*K2E)
#pragma unroll
        for (int mt=0;mt<4;mt++)
#pragma unroll
            for (int reg=0;reg<4;reg++){
                float e0 = exp2_fast(fmaf(acc[mt][0][reg], K2E, -K2E));
                float e1 = exp2_fast(fmaf(acc[mt][1][reg], K2E, -K2E));
                float e2v= exp2_fast(fmaf(acc[mt][2][reg], K2E, -K2E));
                float e3 = exp2_fast(fmaf(acc[mt][3][reg], K2E, -K2E));
                S[mt*4+reg] += (e0+e1)+(e2v+e3);
            }
    }

    // reduce over the 16 col-lanes (disjoint cols, same rows)
#pragma unroll
    for (int off=1; off<16; off<<=1)
#pragma unroll
        for (int s=0;s<16;s++) S[s] += __shfl_xor(S[s], off);

    if (c == 0){
        const int p = chnk*2 + wn;             // 16 partial slots
#pragma unroll
        for (int mt=0;mt<4;mt++)
#pragma unroll
            for (int reg=0;reg<4;reg++){
                int row = i0 + wm*64 + mt*16 + qq*4 + reg;
                Spart[p*BATCH + row] = S[mt*4+reg];
            }
    }
}

// ---------------------------------------------------------------------------
// K5: combine 16 partials/row -> LSE - diag, reduce to accs[1]; the LAST
// block (device-scope counter accs[2]) also writes the two output scalars.
// ---------------------------------------------------------------------------
__global__ __launch_bounds__(256) void
k_finalize(const float* __restrict__ Spart, const float* __restrict__ diag,
           float* __restrict__ accs, float* __restrict__ out_s) {
    int r = blockIdx.x*256 + threadIdx.x;
    float Ssum = 0.f;
#pragma unroll
    for (int p=0;p<16;p++) Ssum += Spart[p*BATCH + r];
    float val = INV_TAU + logf(Ssum) - diag[r];
    for (int off=32; off; off>>=1) val += __shfl_down(val, off);
    if ((threadIdx.x & 63)==0) atomicAdd(&accs[1], val);
    __syncthreads();                       // drains this block's atomics
    if (threadIdx.x == 0){
        __threadfence();
        unsigned int old = __float_as_uint(atomicAdd(&accs[2], 1.0f));
        if (old == __float_as_uint(31.0f)) {   // 32nd (last) block
            __threadfence();
            float a0 = atomicAdd(&accs[0], 0.0f);
            float a1 = atomicAdd(&accs[1], 0.0f);
            out_s[0] = 2.0f*a0 / (float)((size_t)BATCH*LDIM);   // commit+embed
            out_s[1] = a1 / (float)BATCH;                       // contrastive
        }
    }
}

// ---------------------------------------------------------------------------
extern "C" void kernel_launch(void* const* d_in, const int* in_sizes, int n_in,
                              void* d_out, int out_size, void* d_ws, size_t ws_size,
                              hipStream_t stream) {
    const float* z   = (const float*)d_in[0];   // (B, L)
    const float* emb = (const float*)d_in[1];   // (NC, K, SD)
    float* out = (float*)d_out;
    float* out_q       = out;                   // B*L = 4194304
    float* out_scalars = out + 4194304;         // [commit, contrastive]
    float* out_idx     = out + 4194306;         // B*NC as float

    // ws layout (float offsets); ~11 MB total
    float* wsf   = (float*)d_ws;
    float* e2    = wsf;                         // 8192
    float* accs  = wsf + 8192;                  // [commit, contrastive, counter]
    float* diag  = wsf + 8704;                  // 8192
    float* Spart = wsf + 16896;                 // 16 slots used (32 reserved)
    unsigned char* qn8 = (unsigned char*)(Spart + 32*BATCH);   // B*L fp8 (4 MB)
    unsigned char* zn8 = qn8 + (size_t)BATCH*LDIM;             // B*L fp8 (4 MB)
    unsigned short* eh = (unsigned short*)(zn8 + (size_t)BATCH*LDIM); // NC*K*SD bf16
    unsigned short* el = eh + (size_t)NCB*KC*SDIM;             // NC*K*SD bf16

    k_pre    <<<32,          256, 0, stream>>>(emb, e2, eh, el, accs);
    k_argmin <<<dim3(64,8),  256, 0, stream>>>(eh, el, e2, z, emb,
                                               out_q, out_idx, accs);
    k_norm   <<<BATCH,       256, 0, stream>>>(z, out_q, zn8, qn8, diag);
    k_logits <<<dim3(64,8),  256, 0, stream>>>(qn8, zn8, Spart);
    k_finalize<<<32,         256, 0, stream>>>(Spart, diag, accs, out_scalars);
}